// Round 17
// baseline (557.440 us; speedup 1.0000x reference)
//
#include <hip/hip_runtime.h>

// ---------------------------------------------------------------------------
// SelfAttention forward (N=2, L=2048, E=1024, H=16, D=64), f32 in/out.
// Outputs concatenated: out | q | k | v | energy | attention
//
// Round-17 = round-13 (best, 454.0) with ONE variable changed: the
// attention kernel's 8 nontemporal stores become PLAIN stores.
// Mechanism under test: NT = write-around, every 256B segment is an
// independent HBM transaction through TCC's bypass path; plain =
// write-allocate, the 1.07GB stream passes through L2 which coalesces
// and drains full dirty lines (the 6.4 TB/s fill kernel uses plain
// stores). L2 pressure is safe: per-XCD read-hot set (4 heads K+V ~2MB)
// fits in 4MB L2. Everything else byte-identical to round 13.
// ---------------------------------------------------------------------------

typedef __attribute__((ext_vector_type(8))) short     s16x8;   // 8 bf16
typedef __attribute__((ext_vector_type(4))) float     f32x4;
typedef __attribute__((ext_vector_type(8))) unsigned short u16x8;
typedef __attribute__((ext_vector_type(4))) unsigned short u16x4;

#define DEVINL __device__ __forceinline__

DEVINL unsigned short f2b(float f) {           // f32 -> bf16 (RNE)
  unsigned int u = __builtin_bit_cast(unsigned int, f);
  u = (u + 0x7FFFu + ((u >> 16) & 1u)) >> 16;
  return (unsigned short)u;
}

DEVINL s16x8 pack8(float4 a, float4 b) {
  s16x8 r;
  r[0] = (short)f2b(a.x); r[1] = (short)f2b(a.y);
  r[2] = (short)f2b(a.z); r[3] = (short)f2b(a.w);
  r[4] = (short)f2b(b.x); r[5] = (short)f2b(b.y);
  r[6] = (short)f2b(b.z); r[7] = (short)f2b(b.w);
  return r;
}

DEVINL f32x4 mfma16(s16x8 a, s16x8 b, f32x4 c) {
  return __builtin_amdgcn_mfma_f32_16x16x32_bf16(a, b, c, 0, 0, 0);
}

DEVINL void gload16(const void* g, void* l) {  // 16B global -> LDS direct
  __builtin_amdgcn_global_load_lds(
      (const __attribute__((address_space(1))) void*)g,
      (__attribute__((address_space(3))) void*)l, 16, 0, 0);
}

// ---------------------------------------------------------------------------
// 7 f32->bf16 converts in one launch. grid (2048, 7).
// ---------------------------------------------------------------------------
__global__ __launch_bounds__(256) void cvt7_k(
    const float* __restrict__ w0, const float* __restrict__ w1,
    const float* __restrict__ w2, const float* __restrict__ w3,
    const float* __restrict__ x0, const float* __restrict__ x1,
    const float* __restrict__ x2, unsigned short* __restrict__ dw,
    unsigned short* __restrict__ dwo, unsigned short* __restrict__ dx) {
  int z = blockIdx.y;
  const float* s;
  unsigned short* d;
  int n;
  if (z < 3)      { s = (z == 0) ? w0 : (z == 1) ? w1 : w2;
                    d = dw + (size_t)z * 1048576; n = 1048576; }
  else if (z == 3){ s = w3; d = dwo; n = 1048576; }
  else            { s = (z == 4) ? x0 : (z == 5) ? x1 : x2;
                    d = dx + (size_t)(z - 4) * 4194304; n = 4194304; }
  int i = (blockIdx.x * 256 + threadIdx.x) * 8;
  if (i < n) {
    float4 a = *(const float4*)(s + i);
    float4 b = *(const float4*)(s + i + 4);
    u16x8 o;
    o[0] = f2b(a.x); o[1] = f2b(a.y); o[2] = f2b(a.z); o[3] = f2b(a.w);
    o[4] = f2b(b.x); o[5] = f2b(b.y); o[6] = f2b(b.z); o[7] = f2b(b.w);
    *(u16x8*)(d + i) = o;
  }
}

// ---------------------------------------------------------------------------
// m97-style NT GEMM, 128x128 tile (q/k/v projections).
// ---------------------------------------------------------------------------
template<bool QKV>
__global__ __launch_bounds__(256) void gemm_bt(
    const unsigned short* __restrict__ Ab, const unsigned short* __restrict__ Bb,
    const float* __restrict__ b0, const float* __restrict__ b1,
    const float* __restrict__ b2, float* __restrict__ Cf,
    unsigned short* __restrict__ Cb) {
  __shared__ unsigned short lA[4096];   // [128][32] bf16, linear
  __shared__ unsigned short lB[4096];
  int z = QKV ? blockIdx.z : 0;
  const unsigned short* A = Ab + (size_t)z * 4194304;
  const unsigned short* B = Bb + (size_t)z * 1048576;
  const float* bias = (z == 0) ? b0 : (z == 1) ? b1 : b2;
  float* C = Cf + (size_t)z * 4194304;
  unsigned short* Cw = (QKV && z == 1) ? Cb : nullptr;

  int t = threadIdx.x, lane = t & 63, w = t >> 6;
  int m0 = blockIdx.y * 128, n0 = blockIdx.x * 128;
  int wm = (w >> 1) * 64, wn = (w & 1) * 64;
  int lr = lane & 15, g = lane >> 4, kg = g * 8, rb = g * 4;

  int srow = t >> 2, scol = (t & 3) * 8;
  const unsigned short* gA = A + (size_t)(m0 + srow) * 1024 + scol;
  const unsigned short* gB = B + (size_t)(n0 + srow) * 1024 + scol;
  unsigned short* dA = lA + w * 512;
  unsigned short* dB = lB + w * 512;

  f32x4 acc[4][4] = {};

  for (int k0 = 0; k0 < 1024; k0 += 32) {
    gload16(gA,             dA);
    gload16(gA + 64 * 1024, dA + 2048);
    gload16(gB,             dB);
    gload16(gB + 64 * 1024, dB + 2048);
    gA += 32; gB += 32;
    __syncthreads();
    s16x8 af[4], bf[4];
    #pragma unroll
    for (int i = 0; i < 4; i++)
      af[i] = *(const s16x8*)&lA[(wm + i * 16 + lr) * 32 + kg];
    #pragma unroll
    for (int j = 0; j < 4; j++)
      bf[j] = *(const s16x8*)&lB[(wn + j * 16 + lr) * 32 + kg];
    #pragma unroll
    for (int i = 0; i < 4; i++)
      #pragma unroll
      for (int j = 0; j < 4; j++)
        acc[i][j] = mfma16(af[i], bf[j], acc[i][j]);
    __syncthreads();
  }

  #pragma unroll
  for (int i = 0; i < 4; i++) {
    #pragma unroll
    for (int j = 0; j < 4; j++) {
      int col = n0 + wn + j * 16 + lr;
      float bv = bias[col];
      #pragma unroll
      for (int r = 0; r < 4; r++) {
        int row = m0 + wm + i * 16 + rb + r;
        float v = acc[i][j][r] + bv;
        size_t idx = (size_t)row * 1024 + col;
        C[idx] = v;
        if (Cw) Cw[idx] = f2b(v);
      }
    }
  }
}

// ---------------------------------------------------------------------------
// 128x64-tile GEMM for the out-projection: grid (16,32) = 512 blocks.
// ---------------------------------------------------------------------------
__global__ __launch_bounds__(256) void gemm_bt64(
    const unsigned short* __restrict__ Ab, const unsigned short* __restrict__ Bb,
    const float* __restrict__ bias, float* __restrict__ Cf) {
  __shared__ unsigned short lA[4096];   // [128][32]
  __shared__ unsigned short lB[2048];   // [64][32]
  int t = threadIdx.x, lane = t & 63, w = t >> 6;
  int m0 = blockIdx.y * 128, n0 = blockIdx.x * 64;
  int wm = (w >> 1) * 64, wn = (w & 1) * 32;
  int lr = lane & 15, g = lane >> 4, kg = g * 8, rb = g * 4;

  int srow = t >> 2, scol = (t & 3) * 8;
  unsigned short* dA = lA + w * 512;
  unsigned short* dB = lB + w * 512;

  const unsigned short* gA = Ab + (size_t)(m0 + srow) * 1024 + scol;
  const unsigned short* gB = Bb + (size_t)(n0 + srow) * 1024 + scol;
  f32x4 acc[4][2] = {};
  for (int k0 = 0; k0 < 1024; k0 += 32) {
    gload16(gA,             dA);
    gload16(gA + 64 * 1024, dA + 2048);
    gload16(gB,             dB);
    gA += 32; gB += 32;
    __syncthreads();
    s16x8 af[4], bf[2];
    #pragma unroll
    for (int i = 0; i < 4; i++)
      af[i] = *(const s16x8*)&lA[(wm + i * 16 + lr) * 32 + kg];
    #pragma unroll
    for (int j = 0; j < 2; j++)
      bf[j] = *(const s16x8*)&lB[(wn + j * 16 + lr) * 32 + kg];
    #pragma unroll
    for (int i = 0; i < 4; i++)
      #pragma unroll
      for (int j = 0; j < 2; j++)
        acc[i][j] = mfma16(af[i], bf[j], acc[i][j]);
    __syncthreads();
  }
  #pragma unroll
  for (int i = 0; i < 4; i++) {
    #pragma unroll
    for (int j = 0; j < 2; j++) {
      int col = n0 + wn + j * 16 + lr;
      float bv = bias[col];
      #pragma unroll
      for (int r = 0; r < 4; r++) {
        int row = m0 + wm + i * 16 + rb + r;
        Cf[(size_t)row * 1024 + col] = acc[i][j][r] + bv;
      }
    }
  }
}

// ---------------------------------------------------------------------------
// v (f32, [n][l][h*64+d]) -> vt (bf16, [n*16+h][d][l])  (unchanged)
// ---------------------------------------------------------------------------
__global__ __launch_bounds__(256) void transpose_v_k(
    const float* __restrict__ vf, unsigned short* __restrict__ vt) {
  __shared__ unsigned short tile[64][72];
  int nh = blockIdx.y, n = nh >> 4, h = nh & 15;
  int l0 = blockIdx.x * 64;
  int t = threadIdx.x;
  int lr = t >> 2;
  int dc = (t & 3) * 16;
  const float* src = vf + ((size_t)(n * 2048 + l0 + lr)) * 1024 + h * 64 + dc;
  float4 a = *(const float4*)(src);
  float4 b = *(const float4*)(src + 4);
  float4 c = *(const float4*)(src + 8);
  float4 e = *(const float4*)(src + 12);
  float vals[16] = {a.x, a.y, a.z, a.w, b.x, b.y, b.z, b.w,
                    c.x, c.y, c.z, c.w, e.x, e.y, e.z, e.w};
  #pragma unroll
  for (int j = 0; j < 16; j++) tile[dc + j][lr] = f2b(vals[j]);
  __syncthreads();
  int dr = t >> 2;
  int lc = (t & 3) * 16;
  unsigned short* dst = vt + ((size_t)nh * 64 + dr) * 2048 + l0 + lc;
  *(u16x8*)(dst)     = *(const u16x8*)&tile[dr][lc];
  *(u16x8*)(dst + 8) = *(const u16x8*)&tile[dr][lc + 8];
}

// ---------------------------------------------------------------------------
// attn_fused4p_k: round-13 structure, PLAIN stores (single variable change).
// 1024 blocks x 256 thr (4 waves). Wave w owns q-rows q0+w*16..+15;
// wave-private 4KB stage; NO barriers. tau: lane (g,lr), frag jk holds
// S[q=lr][k = c0+(jk>>1)*32+g*8+(jk&1)*4+r]. Stage write uses the tau col
// -> stage holds STANDARD [q][k] tile; extraction (row=ext*4+g, cols
// lr*4..+3) is row-contiguous; stores delayed one chunk (vmcnt-FIFO-safe).
// ---------------------------------------------------------------------------
__global__ __launch_bounds__(256, 3) void attn_fused4p_k(
    const float* __restrict__ qf, const unsigned short* __restrict__ kb,
    const unsigned short* __restrict__ vt, float* __restrict__ energy,
    float* __restrict__ attn, unsigned short* __restrict__ head) {
  __shared__ float stage[4][1024];           // 4KB per wave
  int bid = blockIdx.x;
  int cid = (bid & 7) * 128 + (bid >> 3);    // XCD-contiguous remap (1024/8)
  int nh = cid >> 5, qt = cid & 31;
  int n = nh >> 4, h = nh & 15;
  int t = threadIdx.x, w = t >> 6, lane = t & 63;
  int q0 = qt * 64, wrow = w * 16;
  int lr = lane & 15, g = lane >> 4, kg = g * 8, rb = g * 4;
  int kbase = ((lr >> 2) << 3) + (lr & 3);   // tau's lane-row component

  const float* qrow = qf + ((size_t)(n * 2048 + q0 + wrow + lr)) * 1024 + h * 64;
  s16x8 bq0 = pack8(*(const float4*)(qrow + kg), *(const float4*)(qrow + kg + 4));
  s16x8 bq1 = pack8(*(const float4*)(qrow + 32 + kg),
                    *(const float4*)(qrow + 32 + kg + 4));

  const unsigned short* Kb = kb + (size_t)n * (2048 * 1024) + h * 64;
  const unsigned short* Vb = vt + (size_t)nh * (64 * 2048);
  float* eblk = energy + (size_t)nh * (2048ull * 2048ull) +
                (size_t)(q0 + wrow) * 2048;
  float* ablk = attn + (size_t)nh * (2048ull * 2048ull) +
                (size_t)(q0 + wrow) * 2048;
  float* sb = &stage[w][0];                  // 1024 floats, wave-private
  int colf = lr * 4;                         // extract col (floats)

  // ---- pass 1: energy stores (delayed, PLAIN) overlapped with exp + PV ----
  float lsum = 0.f;
  f32x4 acc_o[4] = {};
  f32x4 er[4];
  int pc = -1;
  for (int c0 = 0; c0 < 2048; c0 += 64) {
    // 1) K loads, tau order (oldest VMEM of the round)
    s16x8 ka[4], kc[4];
    #pragma unroll
    for (int jk = 0; jk < 4; jk++) {
      int kr = c0 + ((jk >> 1) << 5) + ((jk & 1) << 2) + kbase;
      const unsigned short* kp = Kb + (size_t)kr * 1024 + kg;
      ka[jk] = *(const s16x8*)kp;
      kc[jk] = *(const s16x8*)(kp + 32);
    }
    // 2) V loads
    s16x8 vv0[4], vv1[4];
    #pragma unroll
    for (int nf = 0; nf < 4; nf++) {
      const unsigned short* vp = Vb + (size_t)(nf * 16 + lr) * 2048 + c0 + kg;
      vv0[nf] = *(const s16x8*)(vp);
      vv1[nf] = *(const s16x8*)(vp + 32);
    }
    // 3) delayed PLAIN energy stores of previous chunk
    if (pc >= 0) {
      #pragma unroll
      for (int ext = 0; ext < 4; ext++) {
        int row = ext * 4 + g;
        *(f32x4*)(eblk + (size_t)row * 2048 + pc + colf) = er[ext];
      }
    }
    // 4) QK^T (tau layout)
    f32x4 s[4];
    #pragma unroll
    for (int jk = 0; jk < 4; jk++) {
      f32x4 z = {};
      z = mfma16(ka[jk], bq0, z);
      s[jk] = mfma16(kc[jk], bq1, z);
    }
    // 5) stage write with tau col -> standard-layout tile in stage
    #pragma unroll
    for (int jk = 0; jk < 4; jk++) {
      int col = ((jk >> 1) << 5) + kg + ((jk & 1) << 2);
      *(f32x4*)&sb[lr * 64 + (col ^ ((lr & 15) << 2))] = s[jk];
    }
    // 6) exp + lane-local P (tau) + PV
    float e[4][4];
    #pragma unroll
    for (int jk = 0; jk < 4; jk++)
      #pragma unroll
      for (int r = 0; r < 4; r++) {
        e[jk][r] = __expf(s[jk][r] * 0.125f);
        lsum += e[jk][r];
      }
    s16x8 pa0, pa1;
    #pragma unroll
    for (int r = 0; r < 4; r++) {
      pa0[r]     = (short)f2b(e[0][r]);
      pa0[r + 4] = (short)f2b(e[1][r]);
      pa1[r]     = (short)f2b(e[2][r]);
      pa1[r + 4] = (short)f2b(e[3][r]);
    }
    #pragma unroll
    for (int nf = 0; nf < 4; nf++) {
      acc_o[nf] = mfma16(pa0, vv0[nf], acc_o[nf]);
      acc_o[nf] = mfma16(pa1, vv1[nf], acc_o[nf]);
    }
    // 7) extract rows -> registers (stored next round)
    #pragma unroll
    for (int ext = 0; ext < 4; ext++) {
      int row = ext * 4 + g;
      er[ext] = *(const f32x4*)&sb[row * 64 + (colf ^ ((row & 15) << 2))];
    }
    pc = c0;
  }
  { // epilogue: store last chunk's energy
    #pragma unroll
    for (int ext = 0; ext < 4; ext++) {
      int row = ext * 4 + g;
      *(f32x4*)(eblk + (size_t)row * 2048 + pc + colf) = er[ext];
    }
  }

  // row sum for q = q0+wrow+lr (4 lanes share lr); inv stays in registers
  lsum += __shfl_xor(lsum, 16);
  lsum += __shfl_xor(lsum, 32);
  float inv = 1.0f / lsum;
  float invr[4];
  #pragma unroll
  for (int r = 0; r < 4; r++) invr[r] = __shfl(inv, rb + r);

  // head = O / l  (bf16)
  unsigned short* hrow = head + ((size_t)(n * 2048 + q0 + wrow)) * 1024 + h * 64;
  #pragma unroll
  for (int nf = 0; nf < 4; nf++)
    #pragma unroll
    for (int r = 0; r < 4; r++)
      hrow[(size_t)(rb + r) * 1024 + nf * 16 + lr] = f2b(acc_o[nf][r] * invr[r]);

  // ---- pass 2: attention = exp(s/8)*inv, exp*inv applied pre-stage ----
  pc = -1;
  for (int c0 = 0; c0 < 2048; c0 += 64) {
    s16x8 ka[4], kc[4];
    #pragma unroll
    for (int jk = 0; jk < 4; jk++) {
      int kr = c0 + ((jk >> 1) << 5) + ((jk & 1) << 2) + kbase;
      const unsigned short* kp = Kb + (size_t)kr * 1024 + kg;
      ka[jk] = *(const s16x8*)kp;
      kc[jk] = *(const s16x8*)(kp + 32);
    }
    if (pc >= 0) {
      #pragma unroll
      for (int ext = 0; ext < 4; ext++) {
        int row = ext * 4 + g;
        *(f32x4*)(ablk + (size_t)row * 2048 + pc + colf) = er[ext];
      }
    }
    f32x4 s[4];
    #pragma unroll
    for (int jk = 0; jk < 4; jk++) {
      f32x4 z = {};
      z = mfma16(ka[jk], bq0, z);
      s[jk] = mfma16(kc[jk], bq1, z);
    }
    // exp*inv lane-local (q = lr), then stage in standard layout
    #pragma unroll
    for (int jk = 0; jk < 4; jk++) {
      f32x4 av;
      av[0] = __expf(s[jk][0] * 0.125f) * inv;
      av[1] = __expf(s[jk][1] * 0.125f) * inv;
      av[2] = __expf(s[jk][2] * 0.125f) * inv;
      av[3] = __expf(s[jk][3] * 0.125f) * inv;
      int col = ((jk >> 1) << 5) + kg + ((jk & 1) << 2);
      *(f32x4*)&sb[lr * 64 + (col ^ ((lr & 15) << 2))] = av;
    }
    #pragma unroll
    for (int ext = 0; ext < 4; ext++) {
      int row = ext * 4 + g;
      er[ext] = *(const f32x4*)&sb[row * 64 + (colf ^ ((row & 15) << 2))];
    }
    pc = c0;
  }
  { // epilogue: store last chunk's attention
    #pragma unroll
    for (int ext = 0; ext < 4; ext++) {
      int row = ext * 4 + g;
      *(f32x4*)(ablk + (size_t)row * 2048 + pc + colf) = er[ext];
    }
  }
}

// ---------------------------------------------------------------------------
extern "C" void kernel_launch(void* const* d_in, const int* in_sizes, int n_in,
                              void* d_out, int out_size, void* d_ws, size_t ws_size,
                              hipStream_t stream) {
  const float* Vin = (const float*)d_in[0];
  const float* Kin = (const float*)d_in[1];
  const float* Qin = (const float*)d_in[2];
  const float* Wq  = (const float*)d_in[3];
  const float* bq  = (const float*)d_in[4];
  const float* Wk  = (const float*)d_in[5];
  const float* bk  = (const float*)d_in[6];
  const float* Wv  = (const float*)d_in[7];
  const float* bv  = (const float*)d_in[8];
  const float* Wo  = (const float*)d_in[9];
  const float* bo  = (const float*)d_in[10];

  float* out    = (float*)d_out;
  float* qf     = out + 4194304;          // (4096,1024) f32; kf,vf follow
  float* energy = out + 16777216;         // (2,16,2048,2048) f32
  float* attn   = out + 150994944;

  unsigned short* vt = (unsigned short*)out;            // [nh][64][2048]
  unsigned short* kb = (unsigned short*)out + 4194304;
  unsigned short* wqkv = (unsigned short*)energy;
  unsigned short* xqkv = (unsigned short*)(energy + 2097152);
  // d_ws: head bf16 (8MB) + wob bf16 (2MB)
  unsigned short* head = (unsigned short*)d_ws;
  unsigned short* wob  = head + 4194304;

  cvt7_k<<<dim3(2048, 7), 256, 0, stream>>>(
      Wq, Wk, Wv, Wo, Qin, Kin, Vin, wqkv, wob, xqkv);

  gemm_bt<true><<<dim3(8, 32, 3), 256, 0, stream>>>(
      xqkv, wqkv, bq, bk, bv, qf, kb);

  transpose_v_k<<<dim3(32, 32), 256, 0, stream>>>(qf + 8388608, vt);

  attn_fused4p_k<<<dim3(1024), 256, 0, stream>>>(qf, kb, vt, energy, attn, head);

  gemm_bt64<<<dim3(16, 32), 256, 0, stream>>>(head, wob, bo, out);
}

// Round 18
// 527.360 us; speedup vs baseline: 1.0570x; 1.0570x over previous
//
#include <hip/hip_runtime.h>

// ---------------------------------------------------------------------------
// SelfAttention forward (N=2, L=2048, E=1024, H=16, D=64), f32 in/out.
// Outputs concatenated: out | q | k | v | energy | attention
//
// Round-18: PRODUCER/CONSUMER WAVE SPECIALIZATION in the attention kernel.
// attn_pc_k: 1024 blocks x 512 thr (8 waves). Waves 0-3 COMPUTE (r13's
// tau-QK^T + exp + lane-local P + PV body), writing S-tiles into a
// double-buffered LDS tile [16][128] f32 per wave-pair; they issue ZERO
// global stores in the main loops -> their vmcnt waits never couple to
// store retirement. Waves 4-7 STORE: ds_read + NT store only (512B
// segments, 2 rows/instr), no explicit vmcnt waits ever -- HW's
// 63-outstanding cap self-paces them at drain rate. Sync: raw
// asm s_barrier (no vmcnt(0) drain!) + producer-side lgkmcnt(0);
// 17-phase 2-deep pipeline per pass, equal barrier counts on both paths.
// LDS 64KB -> 2 blocks/CU (16 waves/CU).
// All other kernels byte-identical to round 13.
// ---------------------------------------------------------------------------

typedef __attribute__((ext_vector_type(8))) short     s16x8;   // 8 bf16
typedef __attribute__((ext_vector_type(4))) float     f32x4;
typedef __attribute__((ext_vector_type(8))) unsigned short u16x8;
typedef __attribute__((ext_vector_type(4))) unsigned short u16x4;

#define DEVINL __device__ __forceinline__

DEVINL unsigned short f2b(float f) {           // f32 -> bf16 (RNE)
  unsigned int u = __builtin_bit_cast(unsigned int, f);
  u = (u + 0x7FFFu + ((u >> 16) & 1u)) >> 16;
  return (unsigned short)u;
}

DEVINL s16x8 pack8(float4 a, float4 b) {
  s16x8 r;
  r[0] = (short)f2b(a.x); r[1] = (short)f2b(a.y);
  r[2] = (short)f2b(a.z); r[3] = (short)f2b(a.w);
  r[4] = (short)f2b(b.x); r[5] = (short)f2b(b.y);
  r[6] = (short)f2b(b.z); r[7] = (short)f2b(b.w);
  return r;
}

DEVINL f32x4 mfma16(s16x8 a, s16x8 b, f32x4 c) {
  return __builtin_amdgcn_mfma_f32_16x16x32_bf16(a, b, c, 0, 0, 0);
}

DEVINL void gload16(const void* g, void* l) {  // 16B global -> LDS direct
  __builtin_amdgcn_global_load_lds(
      (const __attribute__((address_space(1))) void*)g,
      (__attribute__((address_space(3))) void*)l, 16, 0, 0);
}

// ---------------------------------------------------------------------------
// 7 f32->bf16 converts in one launch. grid (2048, 7).
// ---------------------------------------------------------------------------
__global__ __launch_bounds__(256) void cvt7_k(
    const float* __restrict__ w0, const float* __restrict__ w1,
    const float* __restrict__ w2, const float* __restrict__ w3,
    const float* __restrict__ x0, const float* __restrict__ x1,
    const float* __restrict__ x2, unsigned short* __restrict__ dw,
    unsigned short* __restrict__ dwo, unsigned short* __restrict__ dx) {
  int z = blockIdx.y;
  const float* s;
  unsigned short* d;
  int n;
  if (z < 3)      { s = (z == 0) ? w0 : (z == 1) ? w1 : w2;
                    d = dw + (size_t)z * 1048576; n = 1048576; }
  else if (z == 3){ s = w3; d = dwo; n = 1048576; }
  else            { s = (z == 4) ? x0 : (z == 5) ? x1 : x2;
                    d = dx + (size_t)(z - 4) * 4194304; n = 4194304; }
  int i = (blockIdx.x * 256 + threadIdx.x) * 8;
  if (i < n) {
    float4 a = *(const float4*)(s + i);
    float4 b = *(const float4*)(s + i + 4);
    u16x8 o;
    o[0] = f2b(a.x); o[1] = f2b(a.y); o[2] = f2b(a.z); o[3] = f2b(a.w);
    o[4] = f2b(b.x); o[5] = f2b(b.y); o[6] = f2b(b.z); o[7] = f2b(b.w);
    *(u16x8*)(d + i) = o;
  }
}

// ---------------------------------------------------------------------------
// m97-style NT GEMM, 128x128 tile (q/k/v projections).
// ---------------------------------------------------------------------------
template<bool QKV>
__global__ __launch_bounds__(256) void gemm_bt(
    const unsigned short* __restrict__ Ab, const unsigned short* __restrict__ Bb,
    const float* __restrict__ b0, const float* __restrict__ b1,
    const float* __restrict__ b2, float* __restrict__ Cf,
    unsigned short* __restrict__ Cb) {
  __shared__ unsigned short lA[4096];   // [128][32] bf16, linear
  __shared__ unsigned short lB[4096];
  int z = QKV ? blockIdx.z : 0;
  const unsigned short* A = Ab + (size_t)z * 4194304;
  const unsigned short* B = Bb + (size_t)z * 1048576;
  const float* bias = (z == 0) ? b0 : (z == 1) ? b1 : b2;
  float* C = Cf + (size_t)z * 4194304;
  unsigned short* Cw = (QKV && z == 1) ? Cb : nullptr;

  int t = threadIdx.x, lane = t & 63, w = t >> 6;
  int m0 = blockIdx.y * 128, n0 = blockIdx.x * 128;
  int wm = (w >> 1) * 64, wn = (w & 1) * 64;
  int lr = lane & 15, g = lane >> 4, kg = g * 8, rb = g * 4;

  int srow = t >> 2, scol = (t & 3) * 8;
  const unsigned short* gA = A + (size_t)(m0 + srow) * 1024 + scol;
  const unsigned short* gB = B + (size_t)(n0 + srow) * 1024 + scol;
  unsigned short* dA = lA + w * 512;
  unsigned short* dB = lB + w * 512;

  f32x4 acc[4][4] = {};

  for (int k0 = 0; k0 < 1024; k0 += 32) {
    gload16(gA,             dA);
    gload16(gA + 64 * 1024, dA + 2048);
    gload16(gB,             dB);
    gload16(gB + 64 * 1024, dB + 2048);
    gA += 32; gB += 32;
    __syncthreads();
    s16x8 af[4], bf[4];
    #pragma unroll
    for (int i = 0; i < 4; i++)
      af[i] = *(const s16x8*)&lA[(wm + i * 16 + lr) * 32 + kg];
    #pragma unroll
    for (int j = 0; j < 4; j++)
      bf[j] = *(const s16x8*)&lB[(wn + j * 16 + lr) * 32 + kg];
    #pragma unroll
    for (int i = 0; i < 4; i++)
      #pragma unroll
      for (int j = 0; j < 4; j++)
        acc[i][j] = mfma16(af[i], bf[j], acc[i][j]);
    __syncthreads();
  }

  #pragma unroll
  for (int i = 0; i < 4; i++) {
    #pragma unroll
    for (int j = 0; j < 4; j++) {
      int col = n0 + wn + j * 16 + lr;
      float bv = bias[col];
      #pragma unroll
      for (int r = 0; r < 4; r++) {
        int row = m0 + wm + i * 16 + rb + r;
        float v = acc[i][j][r] + bv;
        size_t idx = (size_t)row * 1024 + col;
        C[idx] = v;
        if (Cw) Cw[idx] = f2b(v);
      }
    }
  }
}

// ---------------------------------------------------------------------------
// 128x64-tile GEMM for the out-projection: grid (16,32) = 512 blocks.
// ---------------------------------------------------------------------------
__global__ __launch_bounds__(256) void gemm_bt64(
    const unsigned short* __restrict__ Ab, const unsigned short* __restrict__ Bb,
    const float* __restrict__ bias, float* __restrict__ Cf) {
  __shared__ unsigned short lA[4096];   // [128][32]
  __shared__ unsigned short lB[2048];   // [64][32]
  int t = threadIdx.x, lane = t & 63, w = t >> 6;
  int m0 = blockIdx.y * 128, n0 = blockIdx.x * 64;
  int wm = (w >> 1) * 64, wn = (w & 1) * 32;
  int lr = lane & 15, g = lane >> 4, kg = g * 8, rb = g * 4;

  int srow = t >> 2, scol = (t & 3) * 8;
  unsigned short* dA = lA + w * 512;
  unsigned short* dB = lB + w * 512;

  const unsigned short* gA = Ab + (size_t)(m0 + srow) * 1024 + scol;
  const unsigned short* gB = Bb + (size_t)(n0 + srow) * 1024 + scol;
  f32x4 acc[4][2] = {};
  for (int k0 = 0; k0 < 1024; k0 += 32) {
    gload16(gA,             dA);
    gload16(gA + 64 * 1024, dA + 2048);
    gload16(gB,             dB);
    gA += 32; gB += 32;
    __syncthreads();
    s16x8 af[4], bf[2];
    #pragma unroll
    for (int i = 0; i < 4; i++)
      af[i] = *(const s16x8*)&lA[(wm + i * 16 + lr) * 32 + kg];
    #pragma unroll
    for (int j = 0; j < 2; j++)
      bf[j] = *(const s16x8*)&lB[(wn + j * 16 + lr) * 32 + kg];
    #pragma unroll
    for (int i = 0; i < 4; i++)
      #pragma unroll
      for (int j = 0; j < 2; j++)
        acc[i][j] = mfma16(af[i], bf[j], acc[i][j]);
    __syncthreads();
  }
  #pragma unroll
  for (int i = 0; i < 4; i++) {
    #pragma unroll
    for (int j = 0; j < 2; j++) {
      int col = n0 + wn + j * 16 + lr;
      float bv = bias[col];
      #pragma unroll
      for (int r = 0; r < 4; r++) {
        int row = m0 + wm + i * 16 + rb + r;
        Cf[(size_t)row * 1024 + col] = acc[i][j][r] + bv;
      }
    }
  }
}

// ---------------------------------------------------------------------------
// v (f32, [n][l][h*64+d]) -> vt (bf16, [n*16+h][d][l])  (unchanged)
// ---------------------------------------------------------------------------
__global__ __launch_bounds__(256) void transpose_v_k(
    const float* __restrict__ vf, unsigned short* __restrict__ vt) {
  __shared__ unsigned short tile[64][72];
  int nh = blockIdx.y, n = nh >> 4, h = nh & 15;
  int l0 = blockIdx.x * 64;
  int t = threadIdx.x;
  int lr = t >> 2;
  int dc = (t & 3) * 16;
  const float* src = vf + ((size_t)(n * 2048 + l0 + lr)) * 1024 + h * 64 + dc;
  float4 a = *(const float4*)(src);
  float4 b = *(const float4*)(src + 4);
  float4 c = *(const float4*)(src + 8);
  float4 e = *(const float4*)(src + 12);
  float vals[16] = {a.x, a.y, a.z, a.w, b.x, b.y, b.z, b.w,
                    c.x, c.y, c.z, c.w, e.x, e.y, e.z, e.w};
  #pragma unroll
  for (int j = 0; j < 16; j++) tile[dc + j][lr] = f2b(vals[j]);
  __syncthreads();
  int dr = t >> 2;
  int lc = (t & 3) * 16;
  unsigned short* dst = vt + ((size_t)nh * 64 + dr) * 2048 + l0 + lc;
  *(u16x8*)(dst)     = *(const u16x8*)&tile[dr][lc];
  *(u16x8*)(dst + 8) = *(const u16x8*)&tile[dr][lc + 8];
}

// ---------------------------------------------------------------------------
// attn_pc_k: producer/consumer wave specialization.
// 1024 blocks x 512 thr. Waves 0-3 compute (pair w), waves 4-7 store (pair w).
// LDS buf[w][2][16][128] f32; quad-swizzle q ^= (row&7) within each row.
// Pipeline per pass: 17 phases; compute fills buf[ph&1] in ph<16; store
// drains buf[(ph-1)&1] in ph>=1; raw s_barrier (memory-clobber asm) between.
// Compute: tau-QK^T (lane (g,lr) frag jk = S[q=lr][k=c0+(jk>>1)*32+g*8+
// (jk&1)*4+r]) -> exp -> lane-local P -> PV; writes S to buf (pass 1) /
// exp*inv to buf (pass 2). NO global stores in main loops.
// Store wave: 8x {ds_read_b128, NT store} per phase (2 rows x 512B each).
// ---------------------------------------------------------------------------
__global__ __launch_bounds__(512, 2) void attn_pc_k(
    const float* __restrict__ qf, const unsigned short* __restrict__ kb,
    const unsigned short* __restrict__ vt, float* __restrict__ energy,
    float* __restrict__ attn, unsigned short* __restrict__ head) {
  __shared__ float buf[4][2][16][128];       // 64 KB
  int bid = blockIdx.x;
  int cid = (bid & 7) * 128 + (bid >> 3);    // XCD-contiguous remap (1024/8)
  int nh = cid >> 5, qt = cid & 31;
  int n = nh >> 4, h = nh & 15;
  int t = threadIdx.x, wv = t >> 6, lane = t & 63;
  int w = wv & 3, wrow = w * 16;
  int q0 = qt * 64;
  int lr = lane & 15, g = lane >> 4, kg = g * 8, rb = g * 4;

  float* eblk = energy + (size_t)nh * (2048ull * 2048ull) +
                (size_t)(q0 + wrow) * 2048;
  float* ablk = attn + (size_t)nh * (2048ull * 2048ull) +
                (size_t)(q0 + wrow) * 2048;

  if (wv < 4) {
    // ================= COMPUTE WAVE =================
    int kbase = ((lr >> 2) << 3) + (lr & 3);     // tau lane-row component
    const float* qrow =
        qf + ((size_t)(n * 2048 + q0 + wrow + lr)) * 1024 + h * 64;
    s16x8 bq0 = pack8(*(const float4*)(qrow + kg),
                      *(const float4*)(qrow + kg + 4));
    s16x8 bq1 = pack8(*(const float4*)(qrow + 32 + kg),
                      *(const float4*)(qrow + 32 + kg + 4));
    const unsigned short* Kb = kb + (size_t)n * (2048 * 1024) + h * 64;
    const unsigned short* Vb = vt + (size_t)nh * (64 * 2048);

    float lsum = 0.f;
    f32x4 acc_o[4] = {};

    // ---- pass 1: S -> buf (+ exp + PV) ----
    for (int ph = 0; ph < 17; ph++) {
      if (ph < 16) {
        float* b = &buf[w][ph & 1][0][0];
        #pragma unroll
        for (int half = 0; half < 2; half++) {
          int c0 = ph * 128 + half * 64;
          s16x8 ka[4], kc[4];
          #pragma unroll
          for (int jk = 0; jk < 4; jk++) {
            int kr = c0 + ((jk >> 1) << 5) + ((jk & 1) << 2) + kbase;
            const unsigned short* kp = Kb + (size_t)kr * 1024 + kg;
            ka[jk] = *(const s16x8*)kp;
            kc[jk] = *(const s16x8*)(kp + 32);
          }
          s16x8 vv0[4], vv1[4];
          #pragma unroll
          for (int nf = 0; nf < 4; nf++) {
            const unsigned short* vp =
                Vb + (size_t)(nf * 16 + lr) * 2048 + c0 + kg;
            vv0[nf] = *(const s16x8*)(vp);
            vv1[nf] = *(const s16x8*)(vp + 32);
          }
          f32x4 s[4];
          #pragma unroll
          for (int jk = 0; jk < 4; jk++) {
            f32x4 z = {};
            z = mfma16(ka[jk], bq0, z);
            s[jk] = mfma16(kc[jk], bq1, z);
          }
          // S tile -> LDS (standard [q][k] layout via tau col; quad swizzle)
          #pragma unroll
          for (int jk = 0; jk < 4; jk++) {
            int q = half * 16 + ((jk >> 1) << 3) + (g << 1) + (jk & 1);
            *(f32x4*)&b[lr * 128 + ((q ^ (lr & 7)) << 2)] = s[jk];
          }
          // exp + lane-local P (tau) + PV
          float e[4][4];
          #pragma unroll
          for (int jk = 0; jk < 4; jk++)
            #pragma unroll
            for (int r = 0; r < 4; r++) {
              e[jk][r] = __expf(s[jk][r] * 0.125f);
              lsum += e[jk][r];
            }
          s16x8 pa0, pa1;
          #pragma unroll
          for (int r = 0; r < 4; r++) {
            pa0[r]     = (short)f2b(e[0][r]);
            pa0[r + 4] = (short)f2b(e[1][r]);
            pa1[r]     = (short)f2b(e[2][r]);
            pa1[r + 4] = (short)f2b(e[3][r]);
          }
          #pragma unroll
          for (int nf = 0; nf < 4; nf++) {
            acc_o[nf] = mfma16(pa0, vv0[nf], acc_o[nf]);
            acc_o[nf] = mfma16(pa1, vv1[nf], acc_o[nf]);
          }
        }
        asm volatile("s_waitcnt lgkmcnt(0)" ::: "memory");
      }
      asm volatile("s_barrier" ::: "memory");
    }

    // row sum for q = q0+wrow+lr (4 lanes share lr)
    lsum += __shfl_xor(lsum, 16);
    lsum += __shfl_xor(lsum, 32);
    float inv = 1.0f / lsum;
    float invr[4];
    #pragma unroll
    for (int r = 0; r < 4; r++) invr[r] = __shfl(inv, rb + r);

    // head = O / l  (bf16)
    unsigned short* hrow =
        head + ((size_t)(n * 2048 + q0 + wrow)) * 1024 + h * 64;
    #pragma unroll
    for (int nf = 0; nf < 4; nf++)
      #pragma unroll
      for (int r = 0; r < 4; r++)
        hrow[(size_t)(rb + r) * 1024 + nf * 16 + lr] =
            f2b(acc_o[nf][r] * invr[r]);

    // ---- pass 2: attention values -> buf ----
    for (int ph = 0; ph < 17; ph++) {
      if (ph < 16) {
        float* b = &buf[w][ph & 1][0][0];
        #pragma unroll
        for (int half = 0; half < 2; half++) {
          int c0 = ph * 128 + half * 64;
          s16x8 ka[4], kc[4];
          #pragma unroll
          for (int jk = 0; jk < 4; jk++) {
            int kr = c0 + ((jk >> 1) << 5) + ((jk & 1) << 2) + kbase;
            const unsigned short* kp = Kb + (size_t)kr * 1024 + kg;
            ka[jk] = *(const s16x8*)kp;
            kc[jk] = *(const s16x8*)(kp + 32);
          }
          #pragma unroll
          for (int jk = 0; jk < 4; jk++) {
            f32x4 z = {};
            z = mfma16(ka[jk], bq0, z);
            f32x4 sv = mfma16(kc[jk], bq1, z);
            f32x4 av;
            av[0] = __expf(sv[0] * 0.125f) * inv;
            av[1] = __expf(sv[1] * 0.125f) * inv;
            av[2] = __expf(sv[2] * 0.125f) * inv;
            av[3] = __expf(sv[3] * 0.125f) * inv;
            int q = half * 16 + ((jk >> 1) << 3) + (g << 1) + (jk & 1);
            *(f32x4*)&b[lr * 128 + ((q ^ (lr & 7)) << 2)] = av;
          }
        }
        asm volatile("s_waitcnt lgkmcnt(0)" ::: "memory");
      }
      asm volatile("s_barrier" ::: "memory");
    }
  } else {
    // ================= STORE WAVE =================
    int qr = lane & 31;                        // quad (col/4) within row
    int rh = lane >> 5;                        // row half select
    // ---- pass 1: energy ----
    for (int ph = 0; ph < 17; ph++) {
      if (ph >= 1) {
        int sc = ph - 1;
        const float* b = &buf[w][sc & 1][0][0];
        #pragma unroll
        for (int i = 0; i < 8; i++) {
          int row = i * 2 + rh;
          f32x4 v = *(const f32x4*)&b[row * 128 + ((qr ^ (row & 7)) << 2)];
          __builtin_nontemporal_store(
              v, (f32x4*)(eblk + (size_t)row * 2048 + sc * 128 + qr * 4));
        }
      }
      asm volatile("s_barrier" ::: "memory");
    }
    // ---- pass 2: attention ----
    for (int ph = 0; ph < 17; ph++) {
      if (ph >= 1) {
        int sc = ph - 1;
        const float* b = &buf[w][sc & 1][0][0];
        #pragma unroll
        for (int i = 0; i < 8; i++) {
          int row = i * 2 + rh;
          f32x4 v = *(const f32x4*)&b[row * 128 + ((qr ^ (row & 7)) << 2)];
          __builtin_nontemporal_store(
              v, (f32x4*)(ablk + (size_t)row * 2048 + sc * 128 + qr * 4));
        }
      }
      asm volatile("s_barrier" ::: "memory");
    }
  }
}

// ---------------------------------------------------------------------------
extern "C" void kernel_launch(void* const* d_in, const int* in_sizes, int n_in,
                              void* d_out, int out_size, void* d_ws, size_t ws_size,
                              hipStream_t stream) {
  const float* Vin = (const float*)d_in[0];
  const float* Kin = (const float*)d_in[1];
  const float* Qin = (const float*)d_in[2];
  const float* Wq  = (const float*)d_in[3];
  const float* bq  = (const float*)d_in[4];
  const float* Wk  = (const float*)d_in[5];
  const float* bk  = (const float*)d_in[6];
  const float* Wv  = (const float*)d_in[7];
  const float* bv  = (const float*)d_in[8];
  const float* Wo  = (const float*)d_in[9];
  const float* bo  = (const float*)d_in[10];

  float* out    = (float*)d_out;
  float* qf     = out + 4194304;          // (4096,1024) f32; kf,vf follow
  float* energy = out + 16777216;         // (2,16,2048,2048) f32
  float* attn   = out + 150994944;

  unsigned short* vt = (unsigned short*)out;            // [nh][64][2048]
  unsigned short* kb = (unsigned short*)out + 4194304;
  unsigned short* wqkv = (unsigned short*)energy;
  unsigned short* xqkv = (unsigned short*)(energy + 2097152);
  // d_ws: head bf16 (8MB) + wob bf16 (2MB)
  unsigned short* head = (unsigned short*)d_ws;
  unsigned short* wob  = head + 4194304;

  cvt7_k<<<dim3(2048, 7), 256, 0, stream>>>(
      Wq, Wk, Wv, Wo, Qin, Kin, Vin, wqkv, wob, xqkv);

  gemm_bt<true><<<dim3(8, 32, 3), 256, 0, stream>>>(
      xqkv, wqkv, bq, bk, bv, qf, kb);

  transpose_v_k<<<dim3(32, 32), 256, 0, stream>>>(qf + 8388608, vt);

  attn_pc_k<<<dim3(1024), 512, 0, stream>>>(qf, kb, vt, energy, attn, head);

  gemm_bt64<<<dim3(16, 32), 256, 0, stream>>>(head, wob, bo, out);
}

// Round 19
// 453.409 us; speedup vs baseline: 1.2294x; 1.1631x over previous
//
#include <hip/hip_runtime.h>

// ---------------------------------------------------------------------------
// SelfAttention forward (N=2, L=2048, E=1024, H=16, D=64), f32 in/out.
// Outputs concatenated: out | q | k | v | energy | attention
//
// FINAL (= round-13, best measured: 454.0 us):
//  0) cvt7: weights + inputs -> bf16.
//  1) qkv projections (m97-style GEMM, grid.z=3); k dual-writes kb bf16.
//  2) transpose vf f32 -> vt bf16 [nh][d][l].
//  3) attn_fused4_k: per-chunk overlap of PV compute with delayed NT energy
//     stores; tau-permuted lane-local P (zero shuffles); wave-private 4KB
//     stage; ZERO barriers; pass 2 recomputes QK^T for attention.
//  4) out-projection: 128x64-tile GEMM (512 blocks).
// Store-path plateau established over 7 structural variants (r12-r18):
// effective NT write BW for this scattered-row pattern ~3.2 TB/s.
// ---------------------------------------------------------------------------

typedef __attribute__((ext_vector_type(8))) short     s16x8;   // 8 bf16
typedef __attribute__((ext_vector_type(4))) float     f32x4;
typedef __attribute__((ext_vector_type(8))) unsigned short u16x8;
typedef __attribute__((ext_vector_type(4))) unsigned short u16x4;

#define DEVINL __device__ __forceinline__

DEVINL unsigned short f2b(float f) {           // f32 -> bf16 (RNE)
  unsigned int u = __builtin_bit_cast(unsigned int, f);
  u = (u + 0x7FFFu + ((u >> 16) & 1u)) >> 16;
  return (unsigned short)u;
}

DEVINL s16x8 pack8(float4 a, float4 b) {
  s16x8 r;
  r[0] = (short)f2b(a.x); r[1] = (short)f2b(a.y);
  r[2] = (short)f2b(a.z); r[3] = (short)f2b(a.w);
  r[4] = (short)f2b(b.x); r[5] = (short)f2b(b.y);
  r[6] = (short)f2b(b.z); r[7] = (short)f2b(b.w);
  return r;
}

DEVINL f32x4 mfma16(s16x8 a, s16x8 b, f32x4 c) {
  return __builtin_amdgcn_mfma_f32_16x16x32_bf16(a, b, c, 0, 0, 0);
}

DEVINL void gload16(const void* g, void* l) {  // 16B global -> LDS direct
  __builtin_amdgcn_global_load_lds(
      (const __attribute__((address_space(1))) void*)g,
      (__attribute__((address_space(3))) void*)l, 16, 0, 0);
}

// ---------------------------------------------------------------------------
// 7 f32->bf16 converts in one launch. grid (2048, 7).
// ---------------------------------------------------------------------------
__global__ __launch_bounds__(256) void cvt7_k(
    const float* __restrict__ w0, const float* __restrict__ w1,
    const float* __restrict__ w2, const float* __restrict__ w3,
    const float* __restrict__ x0, const float* __restrict__ x1,
    const float* __restrict__ x2, unsigned short* __restrict__ dw,
    unsigned short* __restrict__ dwo, unsigned short* __restrict__ dx) {
  int z = blockIdx.y;
  const float* s;
  unsigned short* d;
  int n;
  if (z < 3)      { s = (z == 0) ? w0 : (z == 1) ? w1 : w2;
                    d = dw + (size_t)z * 1048576; n = 1048576; }
  else if (z == 3){ s = w3; d = dwo; n = 1048576; }
  else            { s = (z == 4) ? x0 : (z == 5) ? x1 : x2;
                    d = dx + (size_t)(z - 4) * 4194304; n = 4194304; }
  int i = (blockIdx.x * 256 + threadIdx.x) * 8;
  if (i < n) {
    float4 a = *(const float4*)(s + i);
    float4 b = *(const float4*)(s + i + 4);
    u16x8 o;
    o[0] = f2b(a.x); o[1] = f2b(a.y); o[2] = f2b(a.z); o[3] = f2b(a.w);
    o[4] = f2b(b.x); o[5] = f2b(b.y); o[6] = f2b(b.z); o[7] = f2b(b.w);
    *(u16x8*)(d + i) = o;
  }
}

// ---------------------------------------------------------------------------
// m97-style NT GEMM, 128x128 tile (q/k/v projections).
// ---------------------------------------------------------------------------
template<bool QKV>
__global__ __launch_bounds__(256) void gemm_bt(
    const unsigned short* __restrict__ Ab, const unsigned short* __restrict__ Bb,
    const float* __restrict__ b0, const float* __restrict__ b1,
    const float* __restrict__ b2, float* __restrict__ Cf,
    unsigned short* __restrict__ Cb) {
  __shared__ unsigned short lA[4096];   // [128][32] bf16, linear
  __shared__ unsigned short lB[4096];
  int z = QKV ? blockIdx.z : 0;
  const unsigned short* A = Ab + (size_t)z * 4194304;
  const unsigned short* B = Bb + (size_t)z * 1048576;
  const float* bias = (z == 0) ? b0 : (z == 1) ? b1 : b2;
  float* C = Cf + (size_t)z * 4194304;
  unsigned short* Cw = (QKV && z == 1) ? Cb : nullptr;

  int t = threadIdx.x, lane = t & 63, w = t >> 6;
  int m0 = blockIdx.y * 128, n0 = blockIdx.x * 128;
  int wm = (w >> 1) * 64, wn = (w & 1) * 64;
  int lr = lane & 15, g = lane >> 4, kg = g * 8, rb = g * 4;

  int srow = t >> 2, scol = (t & 3) * 8;
  const unsigned short* gA = A + (size_t)(m0 + srow) * 1024 + scol;
  const unsigned short* gB = B + (size_t)(n0 + srow) * 1024 + scol;
  unsigned short* dA = lA + w * 512;
  unsigned short* dB = lB + w * 512;

  f32x4 acc[4][4] = {};

  for (int k0 = 0; k0 < 1024; k0 += 32) {
    gload16(gA,             dA);
    gload16(gA + 64 * 1024, dA + 2048);
    gload16(gB,             dB);
    gload16(gB + 64 * 1024, dB + 2048);
    gA += 32; gB += 32;
    __syncthreads();
    s16x8 af[4], bf[4];
    #pragma unroll
    for (int i = 0; i < 4; i++)
      af[i] = *(const s16x8*)&lA[(wm + i * 16 + lr) * 32 + kg];
    #pragma unroll
    for (int j = 0; j < 4; j++)
      bf[j] = *(const s16x8*)&lB[(wn + j * 16 + lr) * 32 + kg];
    #pragma unroll
    for (int i = 0; i < 4; i++)
      #pragma unroll
      for (int j = 0; j < 4; j++)
        acc[i][j] = mfma16(af[i], bf[j], acc[i][j]);
    __syncthreads();
  }

  #pragma unroll
  for (int i = 0; i < 4; i++) {
    #pragma unroll
    for (int j = 0; j < 4; j++) {
      int col = n0 + wn + j * 16 + lr;
      float bv = bias[col];
      #pragma unroll
      for (int r = 0; r < 4; r++) {
        int row = m0 + wm + i * 16 + rb + r;
        float v = acc[i][j][r] + bv;
        size_t idx = (size_t)row * 1024 + col;
        C[idx] = v;
        if (Cw) Cw[idx] = f2b(v);
      }
    }
  }
}

// ---------------------------------------------------------------------------
// 128x64-tile GEMM for the out-projection: grid (16,32) = 512 blocks.
// ---------------------------------------------------------------------------
__global__ __launch_bounds__(256) void gemm_bt64(
    const unsigned short* __restrict__ Ab, const unsigned short* __restrict__ Bb,
    const float* __restrict__ bias, float* __restrict__ Cf) {
  __shared__ unsigned short lA[4096];   // [128][32]
  __shared__ unsigned short lB[2048];   // [64][32]
  int t = threadIdx.x, lane = t & 63, w = t >> 6;
  int m0 = blockIdx.y * 128, n0 = blockIdx.x * 64;
  int wm = (w >> 1) * 64, wn = (w & 1) * 32;
  int lr = lane & 15, g = lane >> 4, kg = g * 8, rb = g * 4;

  int srow = t >> 2, scol = (t & 3) * 8;
  unsigned short* dA = lA + w * 512;
  unsigned short* dB = lB + w * 512;

  const unsigned short* gA = Ab + (size_t)(m0 + srow) * 1024 + scol;
  const unsigned short* gB = Bb + (size_t)(n0 + srow) * 1024 + scol;
  f32x4 acc[4][2] = {};
  for (int k0 = 0; k0 < 1024; k0 += 32) {
    gload16(gA,             dA);
    gload16(gA + 64 * 1024, dA + 2048);
    gload16(gB,             dB);
    gA += 32; gB += 32;
    __syncthreads();
    s16x8 af[4], bf[2];
    #pragma unroll
    for (int i = 0; i < 4; i++)
      af[i] = *(const s16x8*)&lA[(wm + i * 16 + lr) * 32 + kg];
    #pragma unroll
    for (int j = 0; j < 2; j++)
      bf[j] = *(const s16x8*)&lB[(wn + j * 16 + lr) * 32 + kg];
    #pragma unroll
    for (int i = 0; i < 4; i++)
      #pragma unroll
      for (int j = 0; j < 2; j++)
        acc[i][j] = mfma16(af[i], bf[j], acc[i][j]);
    __syncthreads();
  }
  #pragma unroll
  for (int i = 0; i < 4; i++) {
    #pragma unroll
    for (int j = 0; j < 2; j++) {
      int col = n0 + wn + j * 16 + lr;
      float bv = bias[col];
      #pragma unroll
      for (int r = 0; r < 4; r++) {
        int row = m0 + wm + i * 16 + rb + r;
        Cf[(size_t)row * 1024 + col] = acc[i][j][r] + bv;
      }
    }
  }
}

// ---------------------------------------------------------------------------
// v (f32, [n][l][h*64+d]) -> vt (bf16, [n*16+h][d][l])
// ---------------------------------------------------------------------------
__global__ __launch_bounds__(256) void transpose_v_k(
    const float* __restrict__ vf, unsigned short* __restrict__ vt) {
  __shared__ unsigned short tile[64][72];
  int nh = blockIdx.y, n = nh >> 4, h = nh & 15;
  int l0 = blockIdx.x * 64;
  int t = threadIdx.x;
  int lr = t >> 2;
  int dc = (t & 3) * 16;
  const float* src = vf + ((size_t)(n * 2048 + l0 + lr)) * 1024 + h * 64 + dc;
  float4 a = *(const float4*)(src);
  float4 b = *(const float4*)(src + 4);
  float4 c = *(const float4*)(src + 8);
  float4 e = *(const float4*)(src + 12);
  float vals[16] = {a.x, a.y, a.z, a.w, b.x, b.y, b.z, b.w,
                    c.x, c.y, c.z, c.w, e.x, e.y, e.z, e.w};
  #pragma unroll
  for (int j = 0; j < 16; j++) tile[dc + j][lr] = f2b(vals[j]);
  __syncthreads();
  int dr = t >> 2;
  int lc = (t & 3) * 16;
  unsigned short* dst = vt + ((size_t)nh * 64 + dr) * 2048 + l0 + lc;
  *(u16x8*)(dst)     = *(const u16x8*)&tile[dr][lc];
  *(u16x8*)(dst + 8) = *(const u16x8*)&tile[dr][lc + 8];
}

// ---------------------------------------------------------------------------
// attn_fused4_k: 1024 blocks x 256 thr (4 waves). Wave w owns q-rows
// q0+w*16..+15; wave-private 4KB stage; NO barriers.
// tau: lane (g,lr), frag jk holds S[q=lr][k = c0+(jk>>1)*32+g*8+(jk&1)*4+r].
// Stage write uses the same tau col -> stage holds STANDARD [q][k] tile;
// extraction (row=ext*4+g, cols lr*4..+3) is row-contiguous for stores.
// ---------------------------------------------------------------------------
__global__ __launch_bounds__(256, 3) void attn_fused4_k(
    const float* __restrict__ qf, const unsigned short* __restrict__ kb,
    const unsigned short* __restrict__ vt, float* __restrict__ energy,
    float* __restrict__ attn, unsigned short* __restrict__ head) {
  __shared__ float stage[4][1024];           // 4KB per wave
  int bid = blockIdx.x;
  int cid = (bid & 7) * 128 + (bid >> 3);    // XCD-contiguous remap (1024/8)
  int nh = cid >> 5, qt = cid & 31;
  int n = nh >> 4, h = nh & 15;
  int t = threadIdx.x, w = t >> 6, lane = t & 63;
  int q0 = qt * 64, wrow = w * 16;
  int lr = lane & 15, g = lane >> 4, kg = g * 8, rb = g * 4;
  int kbase = ((lr >> 2) << 3) + (lr & 3);   // tau's lane-row component

  const float* qrow = qf + ((size_t)(n * 2048 + q0 + wrow + lr)) * 1024 + h * 64;
  s16x8 bq0 = pack8(*(const float4*)(qrow + kg), *(const float4*)(qrow + kg + 4));
  s16x8 bq1 = pack8(*(const float4*)(qrow + 32 + kg),
                    *(const float4*)(qrow + 32 + kg + 4));

  const unsigned short* Kb = kb + (size_t)n * (2048 * 1024) + h * 64;
  const unsigned short* Vb = vt + (size_t)nh * (64 * 2048);
  float* eblk = energy + (size_t)nh * (2048ull * 2048ull) +
                (size_t)(q0 + wrow) * 2048;
  float* ablk = attn + (size_t)nh * (2048ull * 2048ull) +
                (size_t)(q0 + wrow) * 2048;
  float* sb = &stage[w][0];                  // 1024 floats, wave-private
  int colf = lr * 4;                         // extract col (floats)

  // ---- pass 1: energy stores (delayed) overlapped with exp + PV ----
  float lsum = 0.f;
  f32x4 acc_o[4] = {};
  f32x4 er[4];
  int pc = -1;
  for (int c0 = 0; c0 < 2048; c0 += 64) {
    // 1) K loads, tau order (oldest VMEM of the round)
    s16x8 ka[4], kc[4];
    #pragma unroll
    for (int jk = 0; jk < 4; jk++) {
      int kr = c0 + ((jk >> 1) << 5) + ((jk & 1) << 2) + kbase;
      const unsigned short* kp = Kb + (size_t)kr * 1024 + kg;
      ka[jk] = *(const s16x8*)kp;
      kc[jk] = *(const s16x8*)(kp + 32);
    }
    // 2) V loads
    s16x8 vv0[4], vv1[4];
    #pragma unroll
    for (int nf = 0; nf < 4; nf++) {
      const unsigned short* vp = Vb + (size_t)(nf * 16 + lr) * 2048 + c0 + kg;
      vv0[nf] = *(const s16x8*)(vp);
      vv1[nf] = *(const s16x8*)(vp + 32);
    }
    // 3) delayed NT energy stores of previous chunk (younger than the loads
    //    -> the MFMA's load-wait never requires these to retire)
    if (pc >= 0) {
      #pragma unroll
      for (int ext = 0; ext < 4; ext++) {
        int row = ext * 4 + g;
        __builtin_nontemporal_store(
            er[ext], (f32x4*)(eblk + (size_t)row * 2048 + pc + colf));
      }
    }
    // 4) QK^T (tau layout)
    f32x4 s[4];
    #pragma unroll
    for (int jk = 0; jk < 4; jk++) {
      f32x4 z = {};
      z = mfma16(ka[jk], bq0, z);
      s[jk] = mfma16(kc[jk], bq1, z);
    }
    // 5) stage write with tau col -> standard-layout tile in stage
    #pragma unroll
    for (int jk = 0; jk < 4; jk++) {
      int col = ((jk >> 1) << 5) + kg + ((jk & 1) << 2);
      *(f32x4*)&sb[lr * 64 + (col ^ ((lr & 15) << 2))] = s[jk];
    }
    // 6) exp + lane-local P (tau) + PV
    float e[4][4];
    #pragma unroll
    for (int jk = 0; jk < 4; jk++)
      #pragma unroll
      for (int r = 0; r < 4; r++) {
        e[jk][r] = __expf(s[jk][r] * 0.125f);
        lsum += e[jk][r];
      }
    s16x8 pa0, pa1;
    #pragma unroll
    for (int r = 0; r < 4; r++) {
      pa0[r]     = (short)f2b(e[0][r]);
      pa0[r + 4] = (short)f2b(e[1][r]);
      pa1[r]     = (short)f2b(e[2][r]);
      pa1[r + 4] = (short)f2b(e[3][r]);
    }
    #pragma unroll
    for (int nf = 0; nf < 4; nf++) {
      acc_o[nf] = mfma16(pa0, vv0[nf], acc_o[nf]);
      acc_o[nf] = mfma16(pa1, vv1[nf], acc_o[nf]);
    }
    // 7) extract rows -> registers (stored next round)
    #pragma unroll
    for (int ext = 0; ext < 4; ext++) {
      int row = ext * 4 + g;
      er[ext] = *(const f32x4*)&sb[row * 64 + (colf ^ ((row & 15) << 2))];
    }
    pc = c0;
  }
  { // epilogue: store last chunk's energy
    #pragma unroll
    for (int ext = 0; ext < 4; ext++) {
      int row = ext * 4 + g;
      __builtin_nontemporal_store(
          er[ext], (f32x4*)(eblk + (size_t)row * 2048 + pc + colf));
    }
  }

  // row sum for q = q0+wrow+lr (4 lanes share lr); inv stays in registers
  lsum += __shfl_xor(lsum, 16);
  lsum += __shfl_xor(lsum, 32);
  float inv = 1.0f / lsum;
  float invr[4];
  #pragma unroll
  for (int r = 0; r < 4; r++) invr[r] = __shfl(inv, rb + r);

  // head = O / l  (bf16)
  unsigned short* hrow = head + ((size_t)(n * 2048 + q0 + wrow)) * 1024 + h * 64;
  #pragma unroll
  for (int nf = 0; nf < 4; nf++)
    #pragma unroll
    for (int r = 0; r < 4; r++)
      hrow[(size_t)(rb + r) * 1024 + nf * 16 + lr] = f2b(acc_o[nf][r] * invr[r]);

  // ---- pass 2: attention = exp(s/8)*inv, exp*inv applied pre-stage ----
  pc = -1;
  for (int c0 = 0; c0 < 2048; c0 += 64) {
    s16x8 ka[4], kc[4];
    #pragma unroll
    for (int jk = 0; jk < 4; jk++) {
      int kr = c0 + ((jk >> 1) << 5) + ((jk & 1) << 2) + kbase;
      const unsigned short* kp = Kb + (size_t)kr * 1024 + kg;
      ka[jk] = *(const s16x8*)kp;
      kc[jk] = *(const s16x8*)(kp + 32);
    }
    if (pc >= 0) {
      #pragma unroll
      for (int ext = 0; ext < 4; ext++) {
        int row = ext * 4 + g;
        __builtin_nontemporal_store(
            er[ext], (f32x4*)(ablk + (size_t)row * 2048 + pc + colf));
      }
    }
    f32x4 s[4];
    #pragma unroll
    for (int jk = 0; jk < 4; jk++) {
      f32x4 z = {};
      z = mfma16(ka[jk], bq0, z);
      s[jk] = mfma16(kc[jk], bq1, z);
    }
    // exp*inv lane-local (q = lr), then stage in standard layout
    #pragma unroll
    for (int jk = 0; jk < 4; jk++) {
      f32x4 av;
      av[0] = __expf(s[jk][0] * 0.125f) * inv;
      av[1] = __expf(s[jk][1] * 0.125f) * inv;
      av[2] = __expf(s[jk][2] * 0.125f) * inv;
      av[3] = __expf(s[jk][3] * 0.125f) * inv;
      int col = ((jk >> 1) << 5) + kg + ((jk & 1) << 2);
      *(f32x4*)&sb[lr * 64 + (col ^ ((lr & 15) << 2))] = av;
    }
    #pragma unroll
    for (int ext = 0; ext < 4; ext++) {
      int row = ext * 4 + g;
      er[ext] = *(const f32x4*)&sb[row * 64 + (colf ^ ((row & 15) << 2))];
    }
    pc = c0;
  }
  { // epilogue: store last chunk's attention
    #pragma unroll
    for (int ext = 0; ext < 4; ext++) {
      int row = ext * 4 + g;
      __builtin_nontemporal_store(
          er[ext], (f32x4*)(ablk + (size_t)row * 2048 + pc + colf));
    }
  }
}

// ---------------------------------------------------------------------------
extern "C" void kernel_launch(void* const* d_in, const int* in_sizes, int n_in,
                              void* d_out, int out_size, void* d_ws, size_t ws_size,
                              hipStream_t stream) {
  const float* Vin = (const float*)d_in[0];
  const float* Kin = (const float*)d_in[1];
  const float* Qin = (const float*)d_in[2];
  const float* Wq  = (const float*)d_in[3];
  const float* bq  = (const float*)d_in[4];
  const float* Wk  = (const float*)d_in[5];
  const float* bk  = (const float*)d_in[6];
  const float* Wv  = (const float*)d_in[7];
  const float* bv  = (const float*)d_in[8];
  const float* Wo  = (const float*)d_in[9];
  const float* bo  = (const float*)d_in[10];

  float* out    = (float*)d_out;
  float* qf     = out + 4194304;          // (4096,1024) f32; kf,vf follow
  float* energy = out + 16777216;         // (2,16,2048,2048) f32
  float* attn   = out + 150994944;

  unsigned short* vt = (unsigned short*)out;            // [nh][64][2048]
  unsigned short* kb = (unsigned short*)out + 4194304;
  unsigned short* wqkv = (unsigned short*)energy;
  unsigned short* xqkv = (unsigned short*)(energy + 2097152);
  // d_ws: head bf16 (8MB) + wob bf16 (2MB)
  unsigned short* head = (unsigned short*)d_ws;
  unsigned short* wob  = head + 4194304;

  cvt7_k<<<dim3(2048, 7), 256, 0, stream>>>(
      Wq, Wk, Wv, Wo, Qin, Kin, Vin, wqkv, wob, xqkv);

  gemm_bt<true><<<dim3(8, 32, 3), 256, 0, stream>>>(
      xqkv, wqkv, bq, bk, bv, qf, kb);

  transpose_v_k<<<dim3(32, 32), 256, 0, stream>>>(qf + 8388608, vt);

  attn_fused4_k<<<dim3(1024), 256, 0, stream>>>(qf, kb, vt, energy, attn, head);

  gemm_bt64<<<dim3(16, 32), 256, 0, stream>>>(head, wob, bo, out);
}